// Round 6
// baseline (321.933 us; speedup 1.0000x reference)
//
#include <hip/hip_runtime.h>
#include <hip/hip_bf16.h>

// Problem constants
#define B_    2
#define QN    100
#define NP    6
#define WS2   49
#define CC    256
#define NHH   8
#define HDD   32
#define NWIN  600            // Q*Np windows per batch
#define O_PER_B 7526400      // NH*WS2*NWIN*HD

// ws layout (bytes): xT fp32 | wbp bf16 frag-packed [48][8][64][8] | qkv bf16 [1200][49][768] | O fp32
#define XT_BYTES   8388608
#define WB_BYTES   393216
#define QKV_SHORTS_PER_WIN (WS2 * 768)      // 37632 shorts
#define QKV_BYTES  (1200 * WS2 * 768 * 2)   // 90316800

#define SPB_LD 264   // bf16 sp row stride (shorts)

typedef __attribute__((ext_vector_type(8))) short bf16x8;
typedef __attribute__((ext_vector_type(4))) float f32x4;

__device__ __forceinline__ float bf2f(unsigned short u) {
  union { unsigned int i; float f; } v; v.i = ((unsigned int)u) << 16; return v.f;
}
__device__ __forceinline__ unsigned short f2bf(float f) {
  union { float f; unsigned int i; } v; v.f = f;
  unsigned int x = v.i;
  x += 0x7fffu + ((x >> 16) & 1u);   // round-to-nearest-even
  return (unsigned short)(x >> 16);
}

// ---------- K0: x (B,C,H,W) -> xT (B,H*W,C) ----------
__global__ void k0_transpose(const float* __restrict__ x, float* __restrict__ xT) {
  __shared__ float tile[32][33];
  int b  = blockIdx.z;
  int hw0 = blockIdx.x * 32;
  int c0  = blockIdx.y * 32;
  const float* src = x + (size_t)b * CC * 4096;
  float* dst = xT + (size_t)b * 4096 * CC;
  #pragma unroll
  for (int i = threadIdx.y; i < 32; i += 8)
    tile[i][threadIdx.x] = src[(size_t)(c0 + i) * 4096 + hw0 + threadIdx.x];
  __syncthreads();
  #pragma unroll
  for (int i = threadIdx.y; i < 32; i += 8)
    dst[(size_t)(hw0 + i) * CC + c0 + threadIdx.x] = tile[threadIdx.x][i];
}

// ---------- K05: w_qkv fp32 -> bf16, repacked into MFMA B-fragment order ----------
// wbp[((nt*8 + ks)*64 + lane)*8 + i] = bf16(w_qkv[nt*16 + (lane&15)][ks*32 + (lane>>4)*8 + i])
// so a wave's B-frag load is 64 lanes x 16B = 1KB fully contiguous (1 segment, was 16).
__global__ void k05_wpack(const float* __restrict__ w_qkv, unsigned short* __restrict__ wbp) {
  int g = blockIdx.x * 256 + threadIdx.x;       // 0..24575
  int lane = g & 63;
  int ks = (g >> 6) & 7;
  int nt = g >> 9;                              // 0..47
  int n  = nt * 16 + (lane & 15);
  int k0 = ks * 32 + (lane >> 4) * 8;
  const float* src = w_qkv + (size_t)n * CC + k0;
  float4 lo = *(const float4*)(src);
  float4 hi = *(const float4*)(src + 4);
  unsigned short o[8] = { f2bf(lo.x), f2bf(lo.y), f2bf(lo.z), f2bf(lo.w),
                          f2bf(hi.x), f2bf(hi.y), f2bf(hi.z), f2bf(hi.w) };
  *(uint4*)(wbp + (size_t)g * 8) = *(uint4*)o;
}

// ---------- K1: per-window sample + MFMA QKV GEMM -> qkv_ws (bf16, [win][r][j]) ----------
// Round-5: (1) acc live set cut to [4][3] (unified VGPR+AGPR was 180/wave -> 2
// waves/SIMD; now ~115 -> 4 waves/SIMD), (2) B loads from frag-packed wbp
// (1 segment vs 16), (3) XCD swizzle so overlapping windows share per-XCD L2.
__launch_bounds__(256, 4)
__global__ void k1_sample_qkv(const float* __restrict__ xT,
                              const float* __restrict__ polys,
                              const unsigned short* __restrict__ wbp,
                              const float* __restrict__ b_qkv,
                              unsigned short* __restrict__ qkv_ws) {
  __shared__ __align__(16) unsigned short spb[64 * SPB_LD];   // rows 49..63 zeroed
  __shared__ float co_x0[WS2], co_y0[WS2], co_wx[WS2], co_wy[WS2];
  const int tid = threadIdx.x;
  // XCD-aware swizzle: blocks dispatched round-robin to 8 XCDs; give XCD (g&7)
  // 150 consecutive (b,m) so the q-overlapping xT regions stay in its L2.
  const int g = blockIdx.x;                 // 0..1199
  const int w = (g & 7) * 150 + (g >> 3);   // 0..1199
  const int m = w % NWIN;
  const int b = w / NWIN;

  // Phase A: coords for the 49 rows of this window (grid scramble: n = m*49+r)
  if (tid < WS2) {
    int n = m * WS2 + tid;
    int q = n / (WS2 * NP);
    int p = (n / NP) % WS2;
    int a = n % NP;
    const float* pc = polys + (size_t)(b * QN + q) * 12;
    float al = (float)a * 0.2f;
    float py = pc[0];
    float px = pc[6];
    #pragma unroll
    for (int i = 1; i < 6; i++) { py = py * al + pc[i]; px = px * al + pc[6 + i]; }
    py = 2.0f * py - 1.0f;
    px = 2.0f * px - 1.0f;
    float gy = py + (2.0f * (-4.0f + (float)(p / 7) * (7.0f / 6.0f))) * (1.0f / 64.0f);
    float gx = px + (2.0f * (-4.0f + (float)(p % 7) * (7.0f / 6.0f))) * (1.0f / 64.0f);
    // NOTE the reference swap: fx from grid_y, fy from grid_x
    float fx = (gy + 1.0f) * 0.5f * 63.0f;
    float fy = (gx + 1.0f) * 0.5f * 63.0f;
    float x0 = floorf(fx), y0 = floorf(fy);
    co_x0[tid] = x0; co_y0[tid] = y0;
    co_wx[tid] = fx - x0; co_wy[tid] = fy - y0;
  }
  // zero pad rows 49..63
  {
    unsigned int* z = (unsigned int*)(spb + WS2 * SPB_LD);
    for (int i = tid; i < 15 * SPB_LD / 2; i += 256) z[i] = 0u;
  }
  __syncthreads();

  // Phase B: bilinear sampling, thread = channel, bf16 write
  const float* xb = xT + (size_t)b * (4096 * CC);
  #pragma unroll 4
  for (int r = 0; r < WS2; r++) {
    float x0 = co_x0[r], y0 = co_y0[r];
    float wx = co_wx[r], wy = co_wy[r];
    float x1 = x0 + 1.0f, y1 = y0 + 1.0f;
    int xi0 = (int)fminf(fmaxf(x0, 0.0f), 63.0f);
    int yi0 = (int)fminf(fmaxf(y0, 0.0f), 63.0f);
    int xi1 = (int)fminf(fmaxf(x1, 0.0f), 63.0f);
    int yi1 = (int)fminf(fmaxf(y1, 0.0f), 63.0f);
    bool vx0 = (x0 >= 0.0f) && (x0 <= 63.0f);
    bool vx1 = (x1 >= 0.0f) && (x1 <= 63.0f);
    bool vy0 = (y0 >= 0.0f) && (y0 <= 63.0f);
    bool vy1 = (y1 >= 0.0f) && (y1 <= 63.0f);
    float v00 = (vx0 && vy0) ? xb[(yi0 * 64 + xi0) * CC + tid] : 0.0f;
    float v01 = (vx1 && vy0) ? xb[(yi0 * 64 + xi1) * CC + tid] : 0.0f;
    float v10 = (vx0 && vy1) ? xb[(yi1 * 64 + xi0) * CC + tid] : 0.0f;
    float v11 = (vx1 && vy1) ? xb[(yi1 * 64 + xi1) * CC + tid] : 0.0f;
    float s = v00 * (1.0f - wy) * (1.0f - wx) + v01 * (1.0f - wy) * wx
            + v10 * wy * (1.0f - wx) + v11 * wy * wx;
    spb[r * SPB_LD + tid] = f2bf(s);
  }
  __syncthreads();

  // Phase C: MFMA GEMM. Wave wv owns N-cols [wv*192,+192) in 4 chunks of 3
  // N-tiles (acc[4][3] = 48 regs live).
  const int lane = tid & 63;
  const int wv = tid >> 6;
  const int lm = lane & 15;
  const int lg = lane >> 4;
  unsigned short* qd = qkv_ws + (size_t)(b * NWIN + m) * QKV_SHORTS_PER_WIN;

  for (int jc = 0; jc < 4; jc++) {
    const int nt0 = wv * 12 + jc * 3;
    const int ncol0 = nt0 * 16 + lm;
    f32x4 acc[4][3];
    #pragma unroll
    for (int j3 = 0; j3 < 3; j3++) {
      float bias = b_qkv[ncol0 + j3 * 16];
      #pragma unroll
      for (int mt = 0; mt < 4; mt++) acc[mt][j3] = (f32x4){bias, bias, bias, bias};
    }
    #pragma unroll
    for (int ks = 0; ks < 8; ks++) {
      bf16x8 af[4];
      #pragma unroll
      for (int mt = 0; mt < 4; mt++)
        af[mt] = *(const bf16x8*)(spb + (mt * 16 + lm) * SPB_LD + ks * 32 + lg * 8);
      #pragma unroll
      for (int j3 = 0; j3 < 3; j3++) {
        bf16x8 bfrag = *(const bf16x8*)(wbp + (size_t)(((nt0 + j3) * 8 + ks) * 64 + lane) * 8);
        #pragma unroll
        for (int mt = 0; mt < 4; mt++)
          acc[mt][j3] = __builtin_amdgcn_mfma_f32_16x16x32_bf16(af[mt], bfrag, acc[mt][j3], 0, 0, 0);
      }
    }
    // direct store, C-layout rows r = mt*16 + lg*4 + reg, col = ncol0 + j3*16
    #pragma unroll
    for (int mt = 0; mt < 4; mt++) {
      #pragma unroll
      for (int reg = 0; reg < 4; reg++) {
        int r = mt * 16 + lg * 4 + reg;
        if (r < WS2) {
          #pragma unroll
          for (int j3 = 0; j3 < 3; j3++)
            qd[(size_t)r * 768 + ncol0 + j3 * 16] = f2bf(acc[mt][j3][reg]);
        }
      }
    }
  }
}

// ---------- K2: MFMA windowed attention, wave-per-head (2 heads/wave) ----------
#define P_LD 72    // P row stride in shorts
#define V_LD 72    // Vt row stride in shorts
__launch_bounds__(256, 2)
__global__ void k2_attn(const unsigned short* __restrict__ qkv_ws,
                        float* __restrict__ o_ws) {
  __shared__ __align__(16) unsigned short Pbuf[4][64 * P_LD];
  __shared__ __align__(16) unsigned short Vbuf[4][32 * V_LD];
  const int tid = threadIdx.x;
  const int lane = tid & 63;
  const int wv = tid >> 6;
  const int lm = lane & 15;
  const int lg = lane >> 4;
  const int m = blockIdx.x;
  const int b = blockIdx.y;
  const unsigned short* wsrc = qkv_ws + (size_t)(b * NWIN + m) * QKV_SHORTS_PER_WIN;
  const float scale = 0.17677669529663687f;  // 1/sqrt(32)
  unsigned short* P  = Pbuf[wv];
  unsigned short* Vt = Vbuf[wv];

  for (int hh = 0; hh < 2; hh++) {
    const int h = wv * 2 + hh;

    // Stage V^T into LDS: Vt[d][r], rows 49..63 zeroed
    {
      int dd = lane & 31;
      int rb = lane >> 5;
      #pragma unroll
      for (int i = 0; i < 32; i++) {
        int rr = i * 2 + rb;
        unsigned short val = 0;
        if (rr < WS2) val = wsrc[(size_t)rr * 768 + 512 + h * HDD + dd];
        Vt[dd * V_LD + rr] = val;
      }
    }

    // Q/K fragments straight from global [r][j], row-clamped
    bf16x8 qf[4], kf[4];
    #pragma unroll
    for (int t = 0; t < 4; t++) {
      int r = t * 16 + lm; if (r > 48) r = 48;
      qf[t] = *(const bf16x8*)(wsrc + (size_t)r * 768 + h * HDD + lg * 8);
      kf[t] = *(const bf16x8*)(wsrc + (size_t)r * 768 + 256 + h * HDD + lg * 8);
    }

    // S = Q K^T
    f32x4 s[4][4];
    #pragma unroll
    for (int mt = 0; mt < 4; mt++)
      #pragma unroll
      for (int nt = 0; nt < 4; nt++) {
        s[mt][nt] = (f32x4){0.f, 0.f, 0.f, 0.f};
        s[mt][nt] = __builtin_amdgcn_mfma_f32_16x16x32_bf16(qf[mt], kf[nt], s[mt][nt], 0, 0, 0);
      }

    #pragma unroll
    for (int mt = 0; mt < 4; mt++)
      #pragma unroll
      for (int nt = 0; nt < 4; nt++) {
        bool badcol = (nt == 3) && (lm > 0);
        #pragma unroll
        for (int reg = 0; reg < 4; reg++)
          s[mt][nt][reg] = badcol ? -1e30f : s[mt][nt][reg] * scale;
      }

    // softmax over keys (pos_bias is per-row constant: cancels exactly)
    #pragma unroll
    for (int mt = 0; mt < 4; mt++) {
      #pragma unroll
      for (int reg = 0; reg < 4; reg++) {
        float mx = fmaxf(fmaxf(s[mt][0][reg], s[mt][1][reg]),
                         fmaxf(s[mt][2][reg], s[mt][3][reg]));
        #pragma unroll
        for (int off = 1; off < 16; off <<= 1) mx = fmaxf(mx, __shfl_xor(mx, off));
        float sum = 0.0f;
        #pragma unroll
        for (int nt = 0; nt < 4; nt++) {
          float e = __expf(s[mt][nt][reg] - mx);
          s[mt][nt][reg] = e;
          sum += e;
        }
        #pragma unroll
        for (int off = 1; off < 16; off <<= 1) sum += __shfl_xor(sum, off);
        float inv = 1.0f / sum;
        #pragma unroll
        for (int nt = 0; nt < 4; nt++) s[mt][nt][reg] *= inv;
      }
    }

    // P (bf16) -> LDS row-major [p][r2]
    #pragma unroll
    for (int mt = 0; mt < 4; mt++)
      #pragma unroll
      for (int nt = 0; nt < 4; nt++)
        #pragma unroll
        for (int reg = 0; reg < 4; reg++)
          P[(mt * 16 + lg * 4 + reg) * P_LD + nt * 16 + lm] = f2bf(s[mt][nt][reg]);

    // O = P V
    f32x4 o[4][2];
    #pragma unroll
    for (int mt = 0; mt < 4; mt++)
      #pragma unroll
      for (int nt2 = 0; nt2 < 2; nt2++) o[mt][nt2] = (f32x4){0.f, 0.f, 0.f, 0.f};
    #pragma unroll
    for (int ks = 0; ks < 2; ks++) {
      bf16x8 vf[2];
      #pragma unroll
      for (int nt2 = 0; nt2 < 2; nt2++)
        vf[nt2] = *(const bf16x8*)(Vt + (nt2 * 16 + lm) * V_LD + ks * 32 + lg * 8);
      #pragma unroll
      for (int mt = 0; mt < 4; mt++) {
        bf16x8 af = *(const bf16x8*)(P + (mt * 16 + lm) * P_LD + ks * 32 + lg * 8);
        #pragma unroll
        for (int nt2 = 0; nt2 < 2; nt2++)
          o[mt][nt2] = __builtin_amdgcn_mfma_f32_16x16x32_bf16(af, vf[nt2], o[mt][nt2], 0, 0, 0);
      }
    }

    // store O: o_ws[b][((h*49+p)*600+m)*32+d]
    float* ob = o_ws + (size_t)b * O_PER_B + ((size_t)h * WS2 * NWIN + m) * HDD;
    #pragma unroll
    for (int mt = 0; mt < 4; mt++)
      #pragma unroll
      for (int reg = 0; reg < 4; reg++) {
        int p = mt * 16 + lg * 4 + reg;
        if (p < WS2) {
          #pragma unroll
          for (int nt2 = 0; nt2 < 2; nt2++)
            ob[(size_t)p * (NWIN * HDD) + nt2 * 16 + lm] = o[mt][nt2][reg];
        }
      }
  }
}

// ---------- K3: conv (49-tap over p') + projection ----------
__global__ void k3_conv_proj(const float* __restrict__ o_ws,
                             const float* __restrict__ conv_w,
                             const float* __restrict__ conv_b,
                             const float* __restrict__ w_proj,
                             const float* __restrict__ b_proj,
                             float* __restrict__ out) {
  __shared__ float yv[CC];
  __shared__ float cw[WS2];
  const int tid = threadIdx.x;
  const int np = blockIdx.x;
  const int b = blockIdx.y;
  if (tid < WS2) cw[tid] = conv_w[tid];
  __syncthreads();
  const float* base = o_ws + (size_t)b * O_PER_B + (size_t)np * (WS2 * CC);
  float acc = conv_b[0];
  for (int p = 0; p < WS2; p++)
    acc += cw[p] * base[p * CC + tid];
  yv[tid] = acc;
  __syncthreads();
  const float4* y4 = (const float4*)yv;
  const float4* w4 = (const float4*)(w_proj + (size_t)tid * CC);
  float s = b_proj[tid];
  float s2 = 0.0f;
  #pragma unroll 8
  for (int c4 = 0; c4 < 64; c4++) {
    float4 a = y4[c4], wv2 = w4[c4];
    s2 += a.x * wv2.x + a.y * wv2.y + a.z * wv2.z + a.w * wv2.w;
  }
  out[((size_t)(b * NWIN + np)) * CC + tid] = s + s2;
}

extern "C" void kernel_launch(void* const* d_in, const int* in_sizes, int n_in,
                              void* d_out, int out_size, void* d_ws, size_t ws_size,
                              hipStream_t stream) {
  const float* x        = (const float*)d_in[0];
  const float* polys    = (const float*)d_in[1];
  const float* w_qkv    = (const float*)d_in[2];
  const float* b_qkv    = (const float*)d_in[3];
  const float* w_proj   = (const float*)d_in[4];
  const float* b_proj   = (const float*)d_in[5];
  const float* conv_w   = (const float*)d_in[6];
  const float* conv_b   = (const float*)d_in[7];
  float* out = (float*)d_out;

  char* ws = (char*)d_ws;
  float* xT = (float*)ws;
  unsigned short* wbp = (unsigned short*)(ws + XT_BYTES);
  unsigned short* qkv_ws = (unsigned short*)(ws + XT_BYTES + WB_BYTES);
  float* o_ws = (float*)(ws + XT_BYTES + WB_BYTES + QKV_BYTES);

  hipLaunchKernelGGL(k0_transpose, dim3(128, 8, 2), dim3(32, 8), 0, stream, x, xT);
  hipLaunchKernelGGL(k05_wpack, dim3(96), dim3(256), 0, stream, w_qkv, wbp);
  hipLaunchKernelGGL(k1_sample_qkv, dim3(1200), dim3(256), 0, stream,
                     xT, polys, wbp, b_qkv, qkv_ws);
  hipLaunchKernelGGL(k2_attn, dim3(NWIN, B_), dim3(256), 0, stream,
                     qkv_ws, o_ws);
  hipLaunchKernelGGL(k3_conv_proj, dim3(NWIN, B_), dim3(256), 0, stream,
                     o_ws, conv_w, conv_b, w_proj, b_proj, out);
}

// Round 7
// 315.336 us; speedup vs baseline: 1.0209x; 1.0209x over previous
//
#include <hip/hip_runtime.h>
#include <hip/hip_bf16.h>

// Problem constants
#define B_    2
#define QN    100
#define NP    6
#define WS2   49
#define CC    256
#define NHH   8
#define HDD   32
#define NWIN  600            // Q*Np windows per batch
#define O_PER_B 7526400      // NH*WS2*NWIN*HD

// ws layout (bytes): xT fp32 | wbp bf16 frag-packed [48][8][64][8] | qkv bf16 [1200][49][768] | O fp32
#define XT_BYTES   8388608
#define WB_BYTES   393216
#define QKV_SHORTS_PER_WIN (WS2 * 768)      // 37632 shorts
#define QKV_BYTES  (1200 * WS2 * 768 * 2)   // 90316800

#define SPB_LD 264   // bf16 sp row stride (shorts)

typedef __attribute__((ext_vector_type(8))) short bf16x8;
typedef __attribute__((ext_vector_type(4))) float f32x4;

__device__ __forceinline__ float bf2f(unsigned short u) {
  union { unsigned int i; float f; } v; v.i = ((unsigned int)u) << 16; return v.f;
}
__device__ __forceinline__ unsigned short f2bf(float f) {
  union { float f; unsigned int i; } v; v.f = f;
  unsigned int x = v.i;
  x += 0x7fffu + ((x >> 16) & 1u);   // round-to-nearest-even
  return (unsigned short)(x >> 16);
}

// ---------- K0: x (B,C,H,W) -> xT (B,H*W,C) ----------
__global__ void k0_transpose(const float* __restrict__ x, float* __restrict__ xT) {
  __shared__ float tile[32][33];
  int b  = blockIdx.z;
  int hw0 = blockIdx.x * 32;
  int c0  = blockIdx.y * 32;
  const float* src = x + (size_t)b * CC * 4096;
  float* dst = xT + (size_t)b * 4096 * CC;
  #pragma unroll
  for (int i = threadIdx.y; i < 32; i += 8)
    tile[i][threadIdx.x] = src[(size_t)(c0 + i) * 4096 + hw0 + threadIdx.x];
  __syncthreads();
  #pragma unroll
  for (int i = threadIdx.y; i < 32; i += 8)
    dst[(size_t)(hw0 + i) * CC + c0 + threadIdx.x] = tile[threadIdx.x][i];
}

// ---------- K05: w_qkv fp32 -> bf16, repacked into MFMA B-fragment order ----------
// wbp[((nt*8 + ks)*64 + lane)*8 + i] = bf16(w_qkv[nt*16 + (lane&15)][ks*32 + (lane>>4)*8 + i])
__global__ void k05_wpack(const float* __restrict__ w_qkv, unsigned short* __restrict__ wbp) {
  int g = blockIdx.x * 256 + threadIdx.x;       // 0..24575
  int lane = g & 63;
  int ks = (g >> 6) & 7;
  int nt = g >> 9;                              // 0..47
  int n  = nt * 16 + (lane & 15);
  int k0 = ks * 32 + (lane >> 4) * 8;
  const float* src = w_qkv + (size_t)n * CC + k0;
  float4 lo = *(const float4*)(src);
  float4 hi = *(const float4*)(src + 4);
  unsigned short o[8] = { f2bf(lo.x), f2bf(lo.y), f2bf(lo.z), f2bf(lo.w),
                          f2bf(hi.x), f2bf(hi.y), f2bf(hi.z), f2bf(hi.w) };
  *(uint4*)(wbp + (size_t)g * 8) = *(uint4*)o;
}

// ---------- K1: per-window sample + MFMA QKV GEMM -> qkv_ws (bf16, [win][r][j]) ----------
// Round-7: revert XCD swizzle (round-6 FETCH exploded 29->193MB); jc chunks of
// 4 N-tiles so each 128B output line completes within 4 adjacent store instrs
// (round-6 chunks of 3 split every line -> write-allocate refetch + 2x writeback).
// acc[4][4]=64 AGPR + ~64 VGPR = 128 unified -> 4 waves/SIMD.
__launch_bounds__(256, 4)
__global__ void k1_sample_qkv(const float* __restrict__ xT,
                              const float* __restrict__ polys,
                              const unsigned short* __restrict__ wbp,
                              const float* __restrict__ b_qkv,
                              unsigned short* __restrict__ qkv_ws) {
  __shared__ __align__(16) unsigned short spb[64 * SPB_LD];   // rows 49..63 zeroed
  __shared__ float co_x0[WS2], co_y0[WS2], co_wx[WS2], co_wy[WS2];
  const int tid = threadIdx.x;
  const int m = blockIdx.x;
  const int b = blockIdx.y;

  // Phase A: coords for the 49 rows of this window (grid scramble: n = m*49+r)
  if (tid < WS2) {
    int n = m * WS2 + tid;
    int q = n / (WS2 * NP);
    int p = (n / NP) % WS2;
    int a = n % NP;
    const float* pc = polys + (size_t)(b * QN + q) * 12;
    float al = (float)a * 0.2f;
    float py = pc[0];
    float px = pc[6];
    #pragma unroll
    for (int i = 1; i < 6; i++) { py = py * al + pc[i]; px = px * al + pc[6 + i]; }
    py = 2.0f * py - 1.0f;
    px = 2.0f * px - 1.0f;
    float gy = py + (2.0f * (-4.0f + (float)(p / 7) * (7.0f / 6.0f))) * (1.0f / 64.0f);
    float gx = px + (2.0f * (-4.0f + (float)(p % 7) * (7.0f / 6.0f))) * (1.0f / 64.0f);
    // NOTE the reference swap: fx from grid_y, fy from grid_x
    float fx = (gy + 1.0f) * 0.5f * 63.0f;
    float fy = (gx + 1.0f) * 0.5f * 63.0f;
    float x0 = floorf(fx), y0 = floorf(fy);
    co_x0[tid] = x0; co_y0[tid] = y0;
    co_wx[tid] = fx - x0; co_wy[tid] = fy - y0;
  }
  // zero pad rows 49..63
  {
    unsigned int* z = (unsigned int*)(spb + WS2 * SPB_LD);
    for (int i = tid; i < 15 * SPB_LD / 2; i += 256) z[i] = 0u;
  }
  __syncthreads();

  // Phase B: bilinear sampling, thread = channel, bf16 write
  const float* xb = xT + (size_t)b * (4096 * CC);
  #pragma unroll 4
  for (int r = 0; r < WS2; r++) {
    float x0 = co_x0[r], y0 = co_y0[r];
    float wx = co_wx[r], wy = co_wy[r];
    float x1 = x0 + 1.0f, y1 = y0 + 1.0f;
    int xi0 = (int)fminf(fmaxf(x0, 0.0f), 63.0f);
    int yi0 = (int)fminf(fmaxf(y0, 0.0f), 63.0f);
    int xi1 = (int)fminf(fmaxf(x1, 0.0f), 63.0f);
    int yi1 = (int)fminf(fmaxf(y1, 0.0f), 63.0f);
    bool vx0 = (x0 >= 0.0f) && (x0 <= 63.0f);
    bool vx1 = (x1 >= 0.0f) && (x1 <= 63.0f);
    bool vy0 = (y0 >= 0.0f) && (y0 <= 63.0f);
    bool vy1 = (y1 >= 0.0f) && (y1 <= 63.0f);
    float v00 = (vx0 && vy0) ? xb[(yi0 * 64 + xi0) * CC + tid] : 0.0f;
    float v01 = (vx1 && vy0) ? xb[(yi0 * 64 + xi1) * CC + tid] : 0.0f;
    float v10 = (vx0 && vy1) ? xb[(yi1 * 64 + xi0) * CC + tid] : 0.0f;
    float v11 = (vx1 && vy1) ? xb[(yi1 * 64 + xi1) * CC + tid] : 0.0f;
    float s = v00 * (1.0f - wy) * (1.0f - wx) + v01 * (1.0f - wy) * wx
            + v10 * wy * (1.0f - wx) + v11 * wy * wx;
    spb[r * SPB_LD + tid] = f2bf(s);
  }
  __syncthreads();

  // Phase C: MFMA GEMM. Wave wv owns N-tiles [wv*12,+12) in 3 chunks of 4
  // (acc[4][4] = 64 regs live; one chunk = one 128B line per output row).
  const int lane = tid & 63;
  const int wv = tid >> 6;
  const int lm = lane & 15;
  const int lg = lane >> 4;
  unsigned short* qd = qkv_ws + (size_t)(b * NWIN + m) * QKV_SHORTS_PER_WIN;

  for (int jc = 0; jc < 3; jc++) {
    const int nt0 = wv * 12 + jc * 4;
    const int ncol0 = nt0 * 16 + lm;
    f32x4 acc[4][4];
    #pragma unroll
    for (int j4 = 0; j4 < 4; j4++) {
      float bias = b_qkv[ncol0 + j4 * 16];
      #pragma unroll
      for (int mt = 0; mt < 4; mt++) acc[mt][j4] = (f32x4){bias, bias, bias, bias};
    }
    #pragma unroll
    for (int ks = 0; ks < 8; ks++) {
      bf16x8 af[4];
      #pragma unroll
      for (int mt = 0; mt < 4; mt++)
        af[mt] = *(const bf16x8*)(spb + (mt * 16 + lm) * SPB_LD + ks * 32 + lg * 8);
      #pragma unroll
      for (int j4 = 0; j4 < 4; j4++) {
        bf16x8 bfrag = *(const bf16x8*)(wbp + (size_t)(((nt0 + j4) * 8 + ks) * 64 + lane) * 8);
        #pragma unroll
        for (int mt = 0; mt < 4; mt++)
          acc[mt][j4] = __builtin_amdgcn_mfma_f32_16x16x32_bf16(af[mt], bfrag, acc[mt][j4], 0, 0, 0);
      }
    }
    // direct store, C-layout rows r = mt*16 + lg*4 + reg; inner j4 loop covers
    // one full 128B line per row in 4 back-to-back store instructions.
    #pragma unroll
    for (int mt = 0; mt < 4; mt++) {
      #pragma unroll
      for (int reg = 0; reg < 4; reg++) {
        int r = mt * 16 + lg * 4 + reg;
        if (r < WS2) {
          #pragma unroll
          for (int j4 = 0; j4 < 4; j4++)
            qd[(size_t)r * 768 + ncol0 + j4 * 16] = f2bf(acc[mt][j4][reg]);
        }
      }
    }
  }
}

// ---------- K2: MFMA windowed attention, wave-per-head (2 heads/wave) ----------
#define P_LD 72    // P row stride in shorts
#define V_LD 72    // Vt row stride in shorts
__launch_bounds__(256, 2)
__global__ void k2_attn(const unsigned short* __restrict__ qkv_ws,
                        float* __restrict__ o_ws) {
  __shared__ __align__(16) unsigned short Pbuf[4][64 * P_LD];
  __shared__ __align__(16) unsigned short Vbuf[4][32 * V_LD];
  const int tid = threadIdx.x;
  const int lane = tid & 63;
  const int wv = tid >> 6;
  const int lm = lane & 15;
  const int lg = lane >> 4;
  const int m = blockIdx.x;
  const int b = blockIdx.y;
  const unsigned short* wsrc = qkv_ws + (size_t)(b * NWIN + m) * QKV_SHORTS_PER_WIN;
  const float scale = 0.17677669529663687f;  // 1/sqrt(32)
  unsigned short* P  = Pbuf[wv];
  unsigned short* Vt = Vbuf[wv];

  for (int hh = 0; hh < 2; hh++) {
    const int h = wv * 2 + hh;

    // Stage V^T into LDS: Vt[d][r], rows 49..63 zeroed
    {
      int dd = lane & 31;
      int rb = lane >> 5;
      #pragma unroll
      for (int i = 0; i < 32; i++) {
        int rr = i * 2 + rb;
        unsigned short val = 0;
        if (rr < WS2) val = wsrc[(size_t)rr * 768 + 512 + h * HDD + dd];
        Vt[dd * V_LD + rr] = val;
      }
    }

    // Q/K fragments straight from global [r][j], row-clamped
    bf16x8 qf[4], kf[4];
    #pragma unroll
    for (int t = 0; t < 4; t++) {
      int r = t * 16 + lm; if (r > 48) r = 48;
      qf[t] = *(const bf16x8*)(wsrc + (size_t)r * 768 + h * HDD + lg * 8);
      kf[t] = *(const bf16x8*)(wsrc + (size_t)r * 768 + 256 + h * HDD + lg * 8);
    }

    // S = Q K^T
    f32x4 s[4][4];
    #pragma unroll
    for (int mt = 0; mt < 4; mt++)
      #pragma unroll
      for (int nt = 0; nt < 4; nt++) {
        s[mt][nt] = (f32x4){0.f, 0.f, 0.f, 0.f};
        s[mt][nt] = __builtin_amdgcn_mfma_f32_16x16x32_bf16(qf[mt], kf[nt], s[mt][nt], 0, 0, 0);
      }

    #pragma unroll
    for (int mt = 0; mt < 4; mt++)
      #pragma unroll
      for (int nt = 0; nt < 4; nt++) {
        bool badcol = (nt == 3) && (lm > 0);
        #pragma unroll
        for (int reg = 0; reg < 4; reg++)
          s[mt][nt][reg] = badcol ? -1e30f : s[mt][nt][reg] * scale;
      }

    // softmax over keys (pos_bias is per-row constant: cancels exactly)
    #pragma unroll
    for (int mt = 0; mt < 4; mt++) {
      #pragma unroll
      for (int reg = 0; reg < 4; reg++) {
        float mx = fmaxf(fmaxf(s[mt][0][reg], s[mt][1][reg]),
                         fmaxf(s[mt][2][reg], s[mt][3][reg]));
        #pragma unroll
        for (int off = 1; off < 16; off <<= 1) mx = fmaxf(mx, __shfl_xor(mx, off));
        float sum = 0.0f;
        #pragma unroll
        for (int nt = 0; nt < 4; nt++) {
          float e = __expf(s[mt][nt][reg] - mx);
          s[mt][nt][reg] = e;
          sum += e;
        }
        #pragma unroll
        for (int off = 1; off < 16; off <<= 1) sum += __shfl_xor(sum, off);
        float inv = 1.0f / sum;
        #pragma unroll
        for (int nt = 0; nt < 4; nt++) s[mt][nt][reg] *= inv;
      }
    }

    // P (bf16) -> LDS row-major [p][r2]
    #pragma unroll
    for (int mt = 0; mt < 4; mt++)
      #pragma unroll
      for (int nt = 0; nt < 4; nt++)
        #pragma unroll
        for (int reg = 0; reg < 4; reg++)
          P[(mt * 16 + lg * 4 + reg) * P_LD + nt * 16 + lm] = f2bf(s[mt][nt][reg]);

    // O = P V
    f32x4 o[4][2];
    #pragma unroll
    for (int mt = 0; mt < 4; mt++)
      #pragma unroll
      for (int nt2 = 0; nt2 < 2; nt2++) o[mt][nt2] = (f32x4){0.f, 0.f, 0.f, 0.f};
    #pragma unroll
    for (int ks = 0; ks < 2; ks++) {
      bf16x8 vf[2];
      #pragma unroll
      for (int nt2 = 0; nt2 < 2; nt2++)
        vf[nt2] = *(const bf16x8*)(Vt + (nt2 * 16 + lm) * V_LD + ks * 32 + lg * 8);
      #pragma unroll
      for (int mt = 0; mt < 4; mt++) {
        bf16x8 af = *(const bf16x8*)(P + (mt * 16 + lm) * P_LD + ks * 32 + lg * 8);
        #pragma unroll
        for (int nt2 = 0; nt2 < 2; nt2++)
          o[mt][nt2] = __builtin_amdgcn_mfma_f32_16x16x32_bf16(af, vf[nt2], o[mt][nt2], 0, 0, 0);
      }
    }

    // store O: o_ws[b][((h*49+p)*600+m)*32+d]
    float* ob = o_ws + (size_t)b * O_PER_B + ((size_t)h * WS2 * NWIN + m) * HDD;
    #pragma unroll
    for (int mt = 0; mt < 4; mt++)
      #pragma unroll
      for (int reg = 0; reg < 4; reg++) {
        int p = mt * 16 + lg * 4 + reg;
        if (p < WS2) {
          #pragma unroll
          for (int nt2 = 0; nt2 < 2; nt2++)
            ob[(size_t)p * (NWIN * HDD) + nt2 * 16 + lm] = o[mt][nt2][reg];
        }
      }
  }
}

// ---------- K3: conv (49-tap over p') + projection ----------
__global__ void k3_conv_proj(const float* __restrict__ o_ws,
                             const float* __restrict__ conv_w,
                             const float* __restrict__ conv_b,
                             const float* __restrict__ w_proj,
                             const float* __restrict__ b_proj,
                             float* __restrict__ out) {
  __shared__ float yv[CC];
  __shared__ float cw[WS2];
  const int tid = threadIdx.x;
  const int np = blockIdx.x;
  const int b = blockIdx.y;
  if (tid < WS2) cw[tid] = conv_w[tid];
  __syncthreads();
  const float* base = o_ws + (size_t)b * O_PER_B + (size_t)np * (WS2 * CC);
  float acc = conv_b[0];
  for (int p = 0; p < WS2; p++)
    acc += cw[p] * base[p * CC + tid];
  yv[tid] = acc;
  __syncthreads();
  const float4* y4 = (const float4*)yv;
  const float4* w4 = (const float4*)(w_proj + (size_t)tid * CC);
  float s = b_proj[tid];
  float s2 = 0.0f;
  #pragma unroll 8
  for (int c4 = 0; c4 < 64; c4++) {
    float4 a = y4[c4], wv2 = w4[c4];
    s2 += a.x * wv2.x + a.y * wv2.y + a.z * wv2.z + a.w * wv2.w;
  }
  out[((size_t)(b * NWIN + np)) * CC + tid] = s + s2;
}

extern "C" void kernel_launch(void* const* d_in, const int* in_sizes, int n_in,
                              void* d_out, int out_size, void* d_ws, size_t ws_size,
                              hipStream_t stream) {
  const float* x        = (const float*)d_in[0];
  const float* polys    = (const float*)d_in[1];
  const float* w_qkv    = (const float*)d_in[2];
  const float* b_qkv    = (const float*)d_in[3];
  const float* w_proj   = (const float*)d_in[4];
  const float* b_proj   = (const float*)d_in[5];
  const float* conv_w   = (const float*)d_in[6];
  const float* conv_b   = (const float*)d_in[7];
  float* out = (float*)d_out;

  char* ws = (char*)d_ws;
  float* xT = (float*)ws;
  unsigned short* wbp = (unsigned short*)(ws + XT_BYTES);
  unsigned short* qkv_ws = (unsigned short*)(ws + XT_BYTES + WB_BYTES);
  float* o_ws = (float*)(ws + XT_BYTES + WB_BYTES + QKV_BYTES);

  hipLaunchKernelGGL(k0_transpose, dim3(128, 8, 2), dim3(32, 8), 0, stream, x, xT);
  hipLaunchKernelGGL(k05_wpack, dim3(96), dim3(256), 0, stream, w_qkv, wbp);
  hipLaunchKernelGGL(k1_sample_qkv, dim3(NWIN, B_), dim3(256), 0, stream,
                     xT, polys, wbp, b_qkv, qkv_ws);
  hipLaunchKernelGGL(k2_attn, dim3(NWIN, B_), dim3(256), 0, stream,
                     qkv_ws, o_ws);
  hipLaunchKernelGGL(k3_conv_proj, dim3(NWIN, B_), dim3(256), 0, stream,
                     o_ws, conv_w, conv_b, w_proj, b_proj, out);
}

// Round 8
// 283.738 us; speedup vs baseline: 1.1346x; 1.1114x over previous
//
#include <hip/hip_runtime.h>
#include <hip/hip_bf16.h>

// Problem constants
#define B_    2
#define QN    100
#define NP    6
#define WS2   49
#define CC    256
#define NHH   8
#define HDD   32
#define NWIN  600            // Q*Np windows per batch
#define O_PER_B 7526400      // NH*WS2*NWIN*HD

// ws layout (bytes): xT fp32 | wbp bf16 frag-packed [48][8][64][8] | qkv bf16 [1200][49][768] | O fp32
#define XT_BYTES   8388608
#define WB_BYTES   393216
#define QKV_SHORTS_PER_WIN (WS2 * 768)      // 37632 shorts
#define QKV_BYTES  (1200 * WS2 * 768 * 2)   // 90316800

#define SPB_LD 264   // bf16 sp row stride (shorts)
#define CW_LD  72    // per-wave C line-assembly row stride (144B rows, 16B-aligned)

typedef __attribute__((ext_vector_type(8))) short bf16x8;
typedef __attribute__((ext_vector_type(4))) float f32x4;

__device__ __forceinline__ float bf2f(unsigned short u) {
  union { unsigned int i; float f; } v; v.i = ((unsigned int)u) << 16; return v.f;
}
__device__ __forceinline__ unsigned short f2bf(float f) {
  union { float f; unsigned int i; } v; v.f = f;
  unsigned int x = v.i;
  x += 0x7fffu + ((x >> 16) & 1u);   // round-to-nearest-even
  return (unsigned short)(x >> 16);
}

// ---------- K0: x (B,C,H,W) -> xT (B,H*W,C) ----------
__global__ void k0_transpose(const float* __restrict__ x, float* __restrict__ xT) {
  __shared__ float tile[32][33];
  int b  = blockIdx.z;
  int hw0 = blockIdx.x * 32;
  int c0  = blockIdx.y * 32;
  const float* src = x + (size_t)b * CC * 4096;
  float* dst = xT + (size_t)b * 4096 * CC;
  #pragma unroll
  for (int i = threadIdx.y; i < 32; i += 8)
    tile[i][threadIdx.x] = src[(size_t)(c0 + i) * 4096 + hw0 + threadIdx.x];
  __syncthreads();
  #pragma unroll
  for (int i = threadIdx.y; i < 32; i += 8)
    dst[(size_t)(hw0 + i) * CC + c0 + threadIdx.x] = tile[threadIdx.x][i];
}

// ---------- K05: w_qkv fp32 -> bf16, repacked into MFMA B-fragment order ----------
// wbp[((nt*8 + ks)*64 + lane)*8 + i] = bf16(w_qkv[nt*16 + (lane&15)][ks*32 + (lane>>4)*8 + i])
__global__ void k05_wpack(const float* __restrict__ w_qkv, unsigned short* __restrict__ wbp) {
  int g = blockIdx.x * 256 + threadIdx.x;       // 0..24575
  int lane = g & 63;
  int ks = (g >> 6) & 7;
  int nt = g >> 9;                              // 0..47
  int n  = nt * 16 + (lane & 15);
  int k0 = ks * 32 + (lane >> 4) * 8;
  const float* src = w_qkv + (size_t)n * CC + k0;
  float4 lo = *(const float4*)(src);
  float4 hi = *(const float4*)(src + 4);
  unsigned short o[8] = { f2bf(lo.x), f2bf(lo.y), f2bf(lo.z), f2bf(lo.w),
                          f2bf(hi.x), f2bf(hi.y), f2bf(hi.z), f2bf(hi.w) };
  *(uint4*)(wbp + (size_t)g * 8) = *(uint4*)o;
}

// ---------- K1: per-window sample + MFMA QKV GEMM -> qkv_ws (bf16, [win][r][j]) ----------
// Round-8: full-line single-instruction qkv stores. Evidence r4-r7: 2-byte
// partial-line stores amplify (WRITE 88->215MB, FETCH 24->182MB) once
// concurrent blocks/CU > 2 (dirty lines evicted mid-assembly; write-allocate
// refetch). Fix: per-wave LDS line assembly + uint4 stores (8 full 128B lines
// per instr), LDS ~71KB also pins occupancy at the proven-clean 2 blocks/CU.
__launch_bounds__(256, 2)
__global__ void k1_sample_qkv(const float* __restrict__ xT,
                              const float* __restrict__ polys,
                              const unsigned short* __restrict__ wbp,
                              const float* __restrict__ b_qkv,
                              unsigned short* __restrict__ qkv_ws) {
  __shared__ __align__(16) unsigned short spb[64 * SPB_LD];   // rows 49..63 zeroed
  __shared__ __align__(16) unsigned short Cwbuf[4][64 * CW_LD];
  __shared__ float co_x0[WS2], co_y0[WS2], co_wx[WS2], co_wy[WS2];
  const int tid = threadIdx.x;
  const int m = blockIdx.x;
  const int b = blockIdx.y;

  // Phase A: coords for the 49 rows of this window (grid scramble: n = m*49+r)
  if (tid < WS2) {
    int n = m * WS2 + tid;
    int q = n / (WS2 * NP);
    int p = (n / NP) % WS2;
    int a = n % NP;
    const float* pc = polys + (size_t)(b * QN + q) * 12;
    float al = (float)a * 0.2f;
    float py = pc[0];
    float px = pc[6];
    #pragma unroll
    for (int i = 1; i < 6; i++) { py = py * al + pc[i]; px = px * al + pc[6 + i]; }
    py = 2.0f * py - 1.0f;
    px = 2.0f * px - 1.0f;
    float gy = py + (2.0f * (-4.0f + (float)(p / 7) * (7.0f / 6.0f))) * (1.0f / 64.0f);
    float gx = px + (2.0f * (-4.0f + (float)(p % 7) * (7.0f / 6.0f))) * (1.0f / 64.0f);
    // NOTE the reference swap: fx from grid_y, fy from grid_x
    float fx = (gy + 1.0f) * 0.5f * 63.0f;
    float fy = (gx + 1.0f) * 0.5f * 63.0f;
    float x0 = floorf(fx), y0 = floorf(fy);
    co_x0[tid] = x0; co_y0[tid] = y0;
    co_wx[tid] = fx - x0; co_wy[tid] = fy - y0;
  }
  // zero pad rows 49..63
  {
    unsigned int* z = (unsigned int*)(spb + WS2 * SPB_LD);
    for (int i = tid; i < 15 * SPB_LD / 2; i += 256) z[i] = 0u;
  }
  __syncthreads();

  // Phase B: bilinear sampling, thread = channel, bf16 write
  const float* xb = xT + (size_t)b * (4096 * CC);
  #pragma unroll 4
  for (int r = 0; r < WS2; r++) {
    float x0 = co_x0[r], y0 = co_y0[r];
    float wx = co_wx[r], wy = co_wy[r];
    float x1 = x0 + 1.0f, y1 = y0 + 1.0f;
    int xi0 = (int)fminf(fmaxf(x0, 0.0f), 63.0f);
    int yi0 = (int)fminf(fmaxf(y0, 0.0f), 63.0f);
    int xi1 = (int)fminf(fmaxf(x1, 0.0f), 63.0f);
    int yi1 = (int)fminf(fmaxf(y1, 0.0f), 63.0f);
    bool vx0 = (x0 >= 0.0f) && (x0 <= 63.0f);
    bool vx1 = (x1 >= 0.0f) && (x1 <= 63.0f);
    bool vy0 = (y0 >= 0.0f) && (y0 <= 63.0f);
    bool vy1 = (y1 >= 0.0f) && (y1 <= 63.0f);
    float v00 = (vx0 && vy0) ? xb[(yi0 * 64 + xi0) * CC + tid] : 0.0f;
    float v01 = (vx1 && vy0) ? xb[(yi0 * 64 + xi1) * CC + tid] : 0.0f;
    float v10 = (vx0 && vy1) ? xb[(yi1 * 64 + xi0) * CC + tid] : 0.0f;
    float v11 = (vx1 && vy1) ? xb[(yi1 * 64 + xi1) * CC + tid] : 0.0f;
    float s = v00 * (1.0f - wy) * (1.0f - wx) + v01 * (1.0f - wy) * wx
            + v10 * wy * (1.0f - wx) + v11 * wy * wx;
    spb[r * SPB_LD + tid] = f2bf(s);
  }
  __syncthreads();

  // Phase C: MFMA GEMM. Wave wv owns N-tiles [wv*12,+12) in 3 chunks of 4.
  const int lane = tid & 63;
  const int wv = tid >> 6;
  const int lm = lane & 15;
  const int lg = lane >> 4;
  unsigned short* qd = qkv_ws + (size_t)(b * NWIN + m) * QKV_SHORTS_PER_WIN;
  unsigned short* Cw = &Cwbuf[wv][0];

  for (int jc = 0; jc < 3; jc++) {
    const int nt0 = wv * 12 + jc * 4;
    const int ncol0 = nt0 * 16 + lm;
    f32x4 acc[4][4];
    #pragma unroll
    for (int j4 = 0; j4 < 4; j4++) {
      float bias = b_qkv[ncol0 + j4 * 16];
      #pragma unroll
      for (int mt = 0; mt < 4; mt++) acc[mt][j4] = (f32x4){bias, bias, bias, bias};
    }
    #pragma unroll
    for (int ks = 0; ks < 8; ks++) {
      bf16x8 af[4];
      #pragma unroll
      for (int mt = 0; mt < 4; mt++)
        af[mt] = *(const bf16x8*)(spb + (mt * 16 + lm) * SPB_LD + ks * 32 + lg * 8);
      #pragma unroll
      for (int j4 = 0; j4 < 4; j4++) {
        bf16x8 bfrag = *(const bf16x8*)(wbp + (size_t)(((nt0 + j4) * 8 + ks) * 64 + lane) * 8);
        #pragma unroll
        for (int mt = 0; mt < 4; mt++)
          acc[mt][j4] = __builtin_amdgcn_mfma_f32_16x16x32_bf16(af[mt], bfrag, acc[mt][j4], 0, 0, 0);
      }
    }
    // assemble chunk in per-wave LDS (b16 writes; same-wave ds ordering, no barrier)
    #pragma unroll
    for (int mt = 0; mt < 4; mt++) {
      #pragma unroll
      for (int reg = 0; reg < 4; reg++) {
        int r = mt * 16 + lg * 4 + reg;
        #pragma unroll
        for (int j4 = 0; j4 < 4; j4++)
          Cw[r * CW_LD + j4 * 16 + lm] = f2bf(acc[mt][j4][reg]);
      }
    }
    // store full 128B lines: lane = row*8 + seg; 8 complete lines per instr
    const int cbase = nt0 * 16;
    for (int idx = lane; idx < WS2 * 8; idx += 64) {
      int r = idx >> 3, seg = idx & 7;
      *(uint4*)(qd + (size_t)r * 768 + cbase + seg * 8) =
          *(const uint4*)(Cw + r * CW_LD + seg * 8);
    }
  }
}

// ---------- K2: MFMA windowed attention, wave-per-head (2 heads/wave) ----------
#define P_LD 72    // P row stride in shorts
#define V_LD 72    // Vt row stride in shorts
__launch_bounds__(256, 2)
__global__ void k2_attn(const unsigned short* __restrict__ qkv_ws,
                        float* __restrict__ o_ws) {
  __shared__ __align__(16) unsigned short Pbuf[4][64 * P_LD];
  __shared__ __align__(16) unsigned short Vbuf[4][32 * V_LD];
  const int tid = threadIdx.x;
  const int lane = tid & 63;
  const int wv = tid >> 6;
  const int lm = lane & 15;
  const int lg = lane >> 4;
  const int m = blockIdx.x;
  const int b = blockIdx.y;
  const unsigned short* wsrc = qkv_ws + (size_t)(b * NWIN + m) * QKV_SHORTS_PER_WIN;
  const float scale = 0.17677669529663687f;  // 1/sqrt(32)
  unsigned short* P  = Pbuf[wv];
  unsigned short* Vt = Vbuf[wv];

  for (int hh = 0; hh < 2; hh++) {
    const int h = wv * 2 + hh;

    // Stage V^T into LDS: Vt[d][r], rows 49..63 zeroed
    {
      int dd = lane & 31;
      int rb = lane >> 5;
      #pragma unroll
      for (int i = 0; i < 32; i++) {
        int rr = i * 2 + rb;
        unsigned short val = 0;
        if (rr < WS2) val = wsrc[(size_t)rr * 768 + 512 + h * HDD + dd];
        Vt[dd * V_LD + rr] = val;
      }
    }

    // Q/K fragments straight from global [r][j], row-clamped
    bf16x8 qf[4], kf[4];
    #pragma unroll
    for (int t = 0; t < 4; t++) {
      int r = t * 16 + lm; if (r > 48) r = 48;
      qf[t] = *(const bf16x8*)(wsrc + (size_t)r * 768 + h * HDD + lg * 8);
      kf[t] = *(const bf16x8*)(wsrc + (size_t)r * 768 + 256 + h * HDD + lg * 8);
    }

    // S = Q K^T
    f32x4 s[4][4];
    #pragma unroll
    for (int mt = 0; mt < 4; mt++)
      #pragma unroll
      for (int nt = 0; nt < 4; nt++) {
        s[mt][nt] = (f32x4){0.f, 0.f, 0.f, 0.f};
        s[mt][nt] = __builtin_amdgcn_mfma_f32_16x16x32_bf16(qf[mt], kf[nt], s[mt][nt], 0, 0, 0);
      }

    #pragma unroll
    for (int mt = 0; mt < 4; mt++)
      #pragma unroll
      for (int nt = 0; nt < 4; nt++) {
        bool badcol = (nt == 3) && (lm > 0);
        #pragma unroll
        for (int reg = 0; reg < 4; reg++)
          s[mt][nt][reg] = badcol ? -1e30f : s[mt][nt][reg] * scale;
      }

    // softmax over keys (pos_bias is per-row constant: cancels exactly)
    #pragma unroll
    for (int mt = 0; mt < 4; mt++) {
      #pragma unroll
      for (int reg = 0; reg < 4; reg++) {
        float mx = fmaxf(fmaxf(s[mt][0][reg], s[mt][1][reg]),
                         fmaxf(s[mt][2][reg], s[mt][3][reg]));
        #pragma unroll
        for (int off = 1; off < 16; off <<= 1) mx = fmaxf(mx, __shfl_xor(mx, off));
        float sum = 0.0f;
        #pragma unroll
        for (int nt = 0; nt < 4; nt++) {
          float e = __expf(s[mt][nt][reg] - mx);
          s[mt][nt][reg] = e;
          sum += e;
        }
        #pragma unroll
        for (int off = 1; off < 16; off <<= 1) sum += __shfl_xor(sum, off);
        float inv = 1.0f / sum;
        #pragma unroll
        for (int nt = 0; nt < 4; nt++) s[mt][nt][reg] *= inv;
      }
    }

    // P (bf16) -> LDS row-major [p][r2]
    #pragma unroll
    for (int mt = 0; mt < 4; mt++)
      #pragma unroll
      for (int nt = 0; nt < 4; nt++)
        #pragma unroll
        for (int reg = 0; reg < 4; reg++)
          P[(mt * 16 + lg * 4 + reg) * P_LD + nt * 16 + lm] = f2bf(s[mt][nt][reg]);

    // O = P V
    f32x4 o[4][2];
    #pragma unroll
    for (int mt = 0; mt < 4; mt++)
      #pragma unroll
      for (int nt2 = 0; nt2 < 2; nt2++) o[mt][nt2] = (f32x4){0.f, 0.f, 0.f, 0.f};
    #pragma unroll
    for (int ks = 0; ks < 2; ks++) {
      bf16x8 vf[2];
      #pragma unroll
      for (int nt2 = 0; nt2 < 2; nt2++)
        vf[nt2] = *(const bf16x8*)(Vt + (nt2 * 16 + lm) * V_LD + ks * 32 + lg * 8);
      #pragma unroll
      for (int mt = 0; mt < 4; mt++) {
        bf16x8 af = *(const bf16x8*)(P + (mt * 16 + lm) * P_LD + ks * 32 + lg * 8);
        #pragma unroll
        for (int nt2 = 0; nt2 < 2; nt2++)
          o[mt][nt2] = __builtin_amdgcn_mfma_f32_16x16x32_bf16(af, vf[nt2], o[mt][nt2], 0, 0, 0);
      }
    }

    // store O: o_ws[b][((h*49+p)*600+m)*32+d]
    float* ob = o_ws + (size_t)b * O_PER_B + ((size_t)h * WS2 * NWIN + m) * HDD;
    #pragma unroll
    for (int mt = 0; mt < 4; mt++)
      #pragma unroll
      for (int reg = 0; reg < 4; reg++) {
        int p = mt * 16 + lg * 4 + reg;
        if (p < WS2) {
          #pragma unroll
          for (int nt2 = 0; nt2 < 2; nt2++)
            ob[(size_t)p * (NWIN * HDD) + nt2 * 16 + lm] = o[mt][nt2][reg];
        }
      }
  }
}

// ---------- K3: conv (49-tap over p') + projection ----------
__global__ void k3_conv_proj(const float* __restrict__ o_ws,
                             const float* __restrict__ conv_w,
                             const float* __restrict__ conv_b,
                             const float* __restrict__ w_proj,
                             const float* __restrict__ b_proj,
                             float* __restrict__ out) {
  __shared__ float yv[CC];
  __shared__ float cw[WS2];
  const int tid = threadIdx.x;
  const int np = blockIdx.x;
  const int b = blockIdx.y;
  if (tid < WS2) cw[tid] = conv_w[tid];
  __syncthreads();
  const float* base = o_ws + (size_t)b * O_PER_B + (size_t)np * (WS2 * CC);
  float acc = conv_b[0];
  for (int p = 0; p < WS2; p++)
    acc += cw[p] * base[p * CC + tid];
  yv[tid] = acc;
  __syncthreads();
  const float4* y4 = (const float4*)yv;
  const float4* w4 = (const float4*)(w_proj + (size_t)tid * CC);
  float s = b_proj[tid];
  float s2 = 0.0f;
  #pragma unroll 8
  for (int c4 = 0; c4 < 64; c4++) {
    float4 a = y4[c4], wv2 = w4[c4];
    s2 += a.x * wv2.x + a.y * wv2.y + a.z * wv2.z + a.w * wv2.w;
  }
  out[((size_t)(b * NWIN + np)) * CC + tid] = s + s2;
}

extern "C" void kernel_launch(void* const* d_in, const int* in_sizes, int n_in,
                              void* d_out, int out_size, void* d_ws, size_t ws_size,
                              hipStream_t stream) {
  const float* x        = (const float*)d_in[0];
  const float* polys    = (const float*)d_in[1];
  const float* w_qkv    = (const float*)d_in[2];
  const float* b_qkv    = (const float*)d_in[3];
  const float* w_proj   = (const float*)d_in[4];
  const float* b_proj   = (const float*)d_in[5];
  const float* conv_w   = (const float*)d_in[6];
  const float* conv_b   = (const float*)d_in[7];
  float* out = (float*)d_out;

  char* ws = (char*)d_ws;
  float* xT = (float*)ws;
  unsigned short* wbp = (unsigned short*)(ws + XT_BYTES);
  unsigned short* qkv_ws = (unsigned short*)(ws + XT_BYTES + WB_BYTES);
  float* o_ws = (float*)(ws + XT_BYTES + WB_BYTES + QKV_BYTES);

  hipLaunchKernelGGL(k0_transpose, dim3(128, 8, 2), dim3(32, 8), 0, stream, x, xT);
  hipLaunchKernelGGL(k05_wpack, dim3(96), dim3(256), 0, stream, w_qkv, wbp);
  hipLaunchKernelGGL(k1_sample_qkv, dim3(NWIN, B_), dim3(256), 0, stream,
                     xT, polys, wbp, b_qkv, qkv_ws);
  hipLaunchKernelGGL(k2_attn, dim3(NWIN, B_), dim3(256), 0, stream,
                     qkv_ws, o_ws);
  hipLaunchKernelGGL(k3_conv_proj, dim3(NWIN, B_), dim3(256), 0, stream,
                     o_ws, conv_w, conv_b, w_proj, b_proj, out);
}

// Round 9
// 222.159 us; speedup vs baseline: 1.4491x; 1.2772x over previous
//
#include <hip/hip_runtime.h>
#include <hip/hip_bf16.h>

// Problem constants
#define B_    2
#define QN    100
#define NP    6
#define WS2   49
#define CC    256
#define NHH   8
#define HDD   32
#define NWIN  600            // Q*Np windows per batch
#define O_PER_B 7526400      // NH*WS2*NWIN*HD

// ws layout (bytes): xT fp32 | wbp bf16 frag-packed [48][8][64][8] | qkv bf16 [1200][49][768] | O fp32
#define XT_BYTES   8388608
#define WB_BYTES   393216
#define QKV_SHORTS_PER_WIN (WS2 * 768)      // 37632 shorts
#define QKV_BYTES  (1200 * WS2 * 768 * 2)   // 90316800

#define SPB_LD 264   // bf16 sp row stride (shorts)
#define CW_LD  72    // per-wave C line-assembly row stride (144B rows, 16B-aligned)

typedef __attribute__((ext_vector_type(8))) short bf16x8;
typedef __attribute__((ext_vector_type(4))) float f32x4;

__device__ __forceinline__ float bf2f(unsigned short u) {
  union { unsigned int i; float f; } v; v.i = ((unsigned int)u) << 16; return v.f;
}
__device__ __forceinline__ unsigned short f2bf(float f) {
  union { float f; unsigned int i; } v; v.f = f;
  unsigned int x = v.i;
  x += 0x7fffu + ((x >> 16) & 1u);   // round-to-nearest-even
  return (unsigned short)(x >> 16);
}

// ---------- K0: x (B,C,H,W) -> xT (B,H*W,C) ----------
__global__ void k0_transpose(const float* __restrict__ x, float* __restrict__ xT) {
  __shared__ float tile[32][33];
  int b  = blockIdx.z;
  int hw0 = blockIdx.x * 32;
  int c0  = blockIdx.y * 32;
  const float* src = x + (size_t)b * CC * 4096;
  float* dst = xT + (size_t)b * 4096 * CC;
  #pragma unroll
  for (int i = threadIdx.y; i < 32; i += 8)
    tile[i][threadIdx.x] = src[(size_t)(c0 + i) * 4096 + hw0 + threadIdx.x];
  __syncthreads();
  #pragma unroll
  for (int i = threadIdx.y; i < 32; i += 8)
    dst[(size_t)(hw0 + i) * CC + c0 + threadIdx.x] = tile[threadIdx.x][i];
}

// ---------- K05: w_qkv fp32 -> bf16, repacked into MFMA B-fragment order ----------
__global__ void k05_wpack(const float* __restrict__ w_qkv, unsigned short* __restrict__ wbp) {
  int g = blockIdx.x * 256 + threadIdx.x;       // 0..24575
  int lane = g & 63;
  int ks = (g >> 6) & 7;
  int nt = g >> 9;                              // 0..47
  int n  = nt * 16 + (lane & 15);
  int k0 = ks * 32 + (lane >> 4) * 8;
  const float* src = w_qkv + (size_t)n * CC + k0;
  float4 lo = *(const float4*)(src);
  float4 hi = *(const float4*)(src + 4);
  unsigned short o[8] = { f2bf(lo.x), f2bf(lo.y), f2bf(lo.z), f2bf(lo.w),
                          f2bf(hi.x), f2bf(hi.y), f2bf(hi.z), f2bf(hi.w) };
  *(uint4*)(wbp + (size_t)g * 8) = *(uint4*)o;
}

// ---------- K1: per-window sample + MFMA QKV GEMM -> qkv_ws (bf16, [win][r][j]) ----------
// Round-9: (1) Cw assembly shrunk to 16 rows/wave (LDS 71.7->44KB, 2->3
// blocks/CU, dispatch 2.34->1.56 rounds); full-line-per-instruction stores
// KEPT (r8-verified: any sub-line store miss triggers write-allocate fetch).
// (2) depth-1 load pipeline in sampling; register double-buffered bfrag in
// the K-loop so L2 latency hides under the 16 MFMAs.
__launch_bounds__(256, 3)
__global__ void k1_sample_qkv(const float* __restrict__ xT,
                              const float* __restrict__ polys,
                              const unsigned short* __restrict__ wbp,
                              const float* __restrict__ b_qkv,
                              unsigned short* __restrict__ qkv_ws) {
  __shared__ __align__(16) unsigned short spb[64 * SPB_LD];   // rows 49..63 zeroed
  __shared__ __align__(16) unsigned short Cwbuf[4][16 * CW_LD];
  __shared__ float co_x0[WS2], co_y0[WS2], co_wx[WS2], co_wy[WS2];
  const int tid = threadIdx.x;
  const int m = blockIdx.x;
  const int b = blockIdx.y;

  // Phase A: coords for the 49 rows of this window (grid scramble: n = m*49+r)
  if (tid < WS2) {
    int n = m * WS2 + tid;
    int q = n / (WS2 * NP);
    int p = (n / NP) % WS2;
    int a = n % NP;
    const float* pc = polys + (size_t)(b * QN + q) * 12;
    float al = (float)a * 0.2f;
    float py = pc[0];
    float px = pc[6];
    #pragma unroll
    for (int i = 1; i < 6; i++) { py = py * al + pc[i]; px = px * al + pc[6 + i]; }
    py = 2.0f * py - 1.0f;
    px = 2.0f * px - 1.0f;
    float gy = py + (2.0f * (-4.0f + (float)(p / 7) * (7.0f / 6.0f))) * (1.0f / 64.0f);
    float gx = px + (2.0f * (-4.0f + (float)(p % 7) * (7.0f / 6.0f))) * (1.0f / 64.0f);
    // NOTE the reference swap: fx from grid_y, fy from grid_x
    float fx = (gy + 1.0f) * 0.5f * 63.0f;
    float fy = (gx + 1.0f) * 0.5f * 63.0f;
    float x0 = floorf(fx), y0 = floorf(fy);
    co_x0[tid] = x0; co_y0[tid] = y0;
    co_wx[tid] = fx - x0; co_wy[tid] = fy - y0;
  }
  // zero pad rows 49..63
  {
    unsigned int* z = (unsigned int*)(spb + WS2 * SPB_LD);
    for (int i = tid; i < 15 * SPB_LD / 2; i += 256) z[i] = 0u;
  }
  __syncthreads();

  // Phase B: bilinear sampling, thread = channel, depth-1 software pipeline
  const float* xb = xT + (size_t)b * (4096 * CC);
  float n00, n01, n10, n11, wxn, wyn;
  {
    // prologue: issue loads for r=0
    float x0 = co_x0[0], y0 = co_y0[0];
    wxn = co_wx[0]; wyn = co_wy[0];
    float x1 = x0 + 1.0f, y1 = y0 + 1.0f;
    int xi0 = (int)fminf(fmaxf(x0, 0.0f), 63.0f);
    int yi0 = (int)fminf(fmaxf(y0, 0.0f), 63.0f);
    int xi1 = (int)fminf(fmaxf(x1, 0.0f), 63.0f);
    int yi1 = (int)fminf(fmaxf(y1, 0.0f), 63.0f);
    bool vx0 = (x0 >= 0.0f) && (x0 <= 63.0f);
    bool vx1 = (x1 >= 0.0f) && (x1 <= 63.0f);
    bool vy0 = (y0 >= 0.0f) && (y0 <= 63.0f);
    bool vy1 = (y1 >= 0.0f) && (y1 <= 63.0f);
    n00 = (vx0 && vy0) ? xb[(yi0 * 64 + xi0) * CC + tid] : 0.0f;
    n01 = (vx1 && vy0) ? xb[(yi0 * 64 + xi1) * CC + tid] : 0.0f;
    n10 = (vx0 && vy1) ? xb[(yi1 * 64 + xi0) * CC + tid] : 0.0f;
    n11 = (vx1 && vy1) ? xb[(yi1 * 64 + xi1) * CC + tid] : 0.0f;
  }
  for (int r = 0; r < WS2; r++) {
    float c00 = n00, c01 = n01, c10 = n10, c11 = n11;
    float wx = wxn, wy = wyn;
    if (r + 1 < WS2) {
      int rn = r + 1;
      float x0 = co_x0[rn], y0 = co_y0[rn];
      wxn = co_wx[rn]; wyn = co_wy[rn];
      float x1 = x0 + 1.0f, y1 = y0 + 1.0f;
      int xi0 = (int)fminf(fmaxf(x0, 0.0f), 63.0f);
      int yi0 = (int)fminf(fmaxf(y0, 0.0f), 63.0f);
      int xi1 = (int)fminf(fmaxf(x1, 0.0f), 63.0f);
      int yi1 = (int)fminf(fmaxf(y1, 0.0f), 63.0f);
      bool vx0 = (x0 >= 0.0f) && (x0 <= 63.0f);
      bool vx1 = (x1 >= 0.0f) && (x1 <= 63.0f);
      bool vy0 = (y0 >= 0.0f) && (y0 <= 63.0f);
      bool vy1 = (y1 >= 0.0f) && (y1 <= 63.0f);
      n00 = (vx0 && vy0) ? xb[(yi0 * 64 + xi0) * CC + tid] : 0.0f;
      n01 = (vx1 && vy0) ? xb[(yi0 * 64 + xi1) * CC + tid] : 0.0f;
      n10 = (vx0 && vy1) ? xb[(yi1 * 64 + xi0) * CC + tid] : 0.0f;
      n11 = (vx1 && vy1) ? xb[(yi1 * 64 + xi1) * CC + tid] : 0.0f;
    }
    float s = c00 * (1.0f - wy) * (1.0f - wx) + c01 * (1.0f - wy) * wx
            + c10 * wy * (1.0f - wx) + c11 * wy * wx;
    spb[r * SPB_LD + tid] = f2bf(s);
  }
  __syncthreads();

  // Phase C: MFMA GEMM. Wave wv owns N-tiles [wv*12,+12) in 3 chunks of 4.
  const int lane = tid & 63;
  const int wv = tid >> 6;
  const int lm = lane & 15;
  const int lg = lane >> 4;
  unsigned short* qd = qkv_ws + (size_t)(b * NWIN + m) * QKV_SHORTS_PER_WIN;
  unsigned short* Cw = &Cwbuf[wv][0];

  for (int jc = 0; jc < 3; jc++) {
    const int nt0 = wv * 12 + jc * 4;
    const int ncol0 = nt0 * 16 + lm;
    f32x4 acc[4][4];
    #pragma unroll
    for (int j4 = 0; j4 < 4; j4++) {
      float bias = b_qkv[ncol0 + j4 * 16];
      #pragma unroll
      for (int mt = 0; mt < 4; mt++) acc[mt][j4] = (f32x4){bias, bias, bias, bias};
    }
    // register double-buffer for B fragments
    bf16x8 bnx[4];
    #pragma unroll
    for (int j4 = 0; j4 < 4; j4++)
      bnx[j4] = *(const bf16x8*)(wbp + (size_t)(((nt0 + j4) * 8 + 0) * 64 + lane) * 8);
    #pragma unroll
    for (int ks = 0; ks < 8; ks++) {
      bf16x8 bc[4];
      #pragma unroll
      for (int j4 = 0; j4 < 4; j4++) bc[j4] = bnx[j4];
      if (ks < 7) {
        #pragma unroll
        for (int j4 = 0; j4 < 4; j4++)
          bnx[j4] = *(const bf16x8*)(wbp + (size_t)(((nt0 + j4) * 8 + ks + 1) * 64 + lane) * 8);
      }
      bf16x8 af[4];
      #pragma unroll
      for (int mt = 0; mt < 4; mt++)
        af[mt] = *(const bf16x8*)(spb + (mt * 16 + lm) * SPB_LD + ks * 32 + lg * 8);
      #pragma unroll
      for (int j4 = 0; j4 < 4; j4++)
        #pragma unroll
        for (int mt = 0; mt < 4; mt++)
          acc[mt][j4] = __builtin_amdgcn_mfma_f32_16x16x32_bf16(af[mt], bc[j4], acc[mt][j4], 0, 0, 0);
    }
    // per-mt 16-row assembly + full-line stores (8 lines per uint4 instr)
    const int cbase = nt0 * 16;
    #pragma unroll
    for (int mt = 0; mt < 4; mt++) {
      #pragma unroll
      for (int reg = 0; reg < 4; reg++) {
        int rr = lg * 4 + reg;   // row within tile
        #pragma unroll
        for (int j4 = 0; j4 < 4; j4++)
          Cw[rr * CW_LD + j4 * 16 + lm] = f2bf(acc[mt][j4][reg]);
      }
      int r0 = mt * 16;
      #pragma unroll
      for (int half = 0; half < 2; half++) {
        int idx = half * 64 + lane;
        int r16 = idx >> 3;       // 0..15
        int seg = idx & 7;
        int r = r0 + r16;
        if (r < WS2)
          *(uint4*)(qd + (size_t)r * 768 + cbase + seg * 8) =
              *(const uint4*)(Cw + r16 * CW_LD + seg * 8);
      }
    }
  }
}

// ---------- K2: MFMA windowed attention, wave-per-head (2 heads/wave) ----------
// Round-9: LDS shrunk 55.3->45.6KB (3 blocks/CU): single shared block, P
// region 49 rows/wave with write-guard (stray A-frag reads of rows 49..63 hit
// defined LDS; they only feed O rows >=49 which are never stored).
#define P_LD 72    // P row stride in shorts
#define V_LD 72    // Vt row stride in shorts
#define P_WAVE (WS2 * P_LD)          // 3528 shorts per wave
#define V_OFF  (4 * P_WAVE)          // 14112 shorts
#define V_WAVE (32 * V_LD)           // 2304 shorts per wave
__launch_bounds__(256, 3)
__global__ void k2_attn(const unsigned short* __restrict__ qkv_ws,
                        float* __restrict__ o_ws) {
  __shared__ __align__(16) unsigned short lds[V_OFF + 4 * V_WAVE];  // 46656 B
  const int tid = threadIdx.x;
  const int lane = tid & 63;
  const int wv = tid >> 6;
  const int lm = lane & 15;
  const int lg = lane >> 4;
  const int m = blockIdx.x;
  const int b = blockIdx.y;
  const unsigned short* wsrc = qkv_ws + (size_t)(b * NWIN + m) * QKV_SHORTS_PER_WIN;
  const float scale = 0.17677669529663687f;  // 1/sqrt(32)
  unsigned short* P  = lds + wv * P_WAVE;
  unsigned short* Vt = lds + V_OFF + wv * V_WAVE;

  for (int hh = 0; hh < 2; hh++) {
    const int h = wv * 2 + hh;

    // Stage V^T into LDS: Vt[d][r], rows 49..63 zeroed
    {
      int dd = lane & 31;
      int rb = lane >> 5;
      #pragma unroll
      for (int i = 0; i < 32; i++) {
        int rr = i * 2 + rb;
        unsigned short val = 0;
        if (rr < WS2) val = wsrc[(size_t)rr * 768 + 512 + h * HDD + dd];
        Vt[dd * V_LD + rr] = val;
      }
    }

    // Q/K fragments straight from global [r][j], row-clamped
    bf16x8 qf[4], kf[4];
    #pragma unroll
    for (int t = 0; t < 4; t++) {
      int r = t * 16 + lm; if (r > 48) r = 48;
      qf[t] = *(const bf16x8*)(wsrc + (size_t)r * 768 + h * HDD + lg * 8);
      kf[t] = *(const bf16x8*)(wsrc + (size_t)r * 768 + 256 + h * HDD + lg * 8);
    }

    // S = Q K^T
    f32x4 s[4][4];
    #pragma unroll
    for (int mt = 0; mt < 4; mt++)
      #pragma unroll
      for (int nt = 0; nt < 4; nt++) {
        s[mt][nt] = (f32x4){0.f, 0.f, 0.f, 0.f};
        s[mt][nt] = __builtin_amdgcn_mfma_f32_16x16x32_bf16(qf[mt], kf[nt], s[mt][nt], 0, 0, 0);
      }

    #pragma unroll
    for (int mt = 0; mt < 4; mt++)
      #pragma unroll
      for (int nt = 0; nt < 4; nt++) {
        bool badcol = (nt == 3) && (lm > 0);
        #pragma unroll
        for (int reg = 0; reg < 4; reg++)
          s[mt][nt][reg] = badcol ? -1e30f : s[mt][nt][reg] * scale;
      }

    // softmax over keys (pos_bias is per-row constant: cancels exactly)
    #pragma unroll
    for (int mt = 0; mt < 4; mt++) {
      #pragma unroll
      for (int reg = 0; reg < 4; reg++) {
        float mx = fmaxf(fmaxf(s[mt][0][reg], s[mt][1][reg]),
                         fmaxf(s[mt][2][reg], s[mt][3][reg]));
        #pragma unroll
        for (int off = 1; off < 16; off <<= 1) mx = fmaxf(mx, __shfl_xor(mx, off));
        float sum = 0.0f;
        #pragma unroll
        for (int nt = 0; nt < 4; nt++) {
          float e = __expf(s[mt][nt][reg] - mx);
          s[mt][nt][reg] = e;
          sum += e;
        }
        #pragma unroll
        for (int off = 1; off < 16; off <<= 1) sum += __shfl_xor(sum, off);
        float inv = 1.0f / sum;
        #pragma unroll
        for (int nt = 0; nt < 4; nt++) s[mt][nt][reg] *= inv;
      }
    }

    // P (bf16) -> LDS row-major [p][r2], rows >=49 suppressed (region is 49 rows)
    #pragma unroll
    for (int mt = 0; mt < 4; mt++)
      #pragma unroll
      for (int nt = 0; nt < 4; nt++)
        #pragma unroll
        for (int reg = 0; reg < 4; reg++) {
          int p = mt * 16 + lg * 4 + reg;
          if (p < WS2) P[p * P_LD + nt * 16 + lm] = f2bf(s[mt][nt][reg]);
        }

    // O = P V
    f32x4 o[4][2];
    #pragma unroll
    for (int mt = 0; mt < 4; mt++)
      #pragma unroll
      for (int nt2 = 0; nt2 < 2; nt2++) o[mt][nt2] = (f32x4){0.f, 0.f, 0.f, 0.f};
    #pragma unroll
    for (int ks = 0; ks < 2; ks++) {
      bf16x8 vf[2];
      #pragma unroll
      for (int nt2 = 0; nt2 < 2; nt2++)
        vf[nt2] = *(const bf16x8*)(Vt + (nt2 * 16 + lm) * V_LD + ks * 32 + lg * 8);
      #pragma unroll
      for (int mt = 0; mt < 4; mt++) {
        bf16x8 af = *(const bf16x8*)(P + (mt * 16 + lm) * P_LD + ks * 32 + lg * 8);
        #pragma unroll
        for (int nt2 = 0; nt2 < 2; nt2++)
          o[mt][nt2] = __builtin_amdgcn_mfma_f32_16x16x32_bf16(af, vf[nt2], o[mt][nt2], 0, 0, 0);
      }
    }

    // store O: o_ws[b][((h*49+p)*600+m)*32+d]
    float* ob = o_ws + (size_t)b * O_PER_B + ((size_t)h * WS2 * NWIN + m) * HDD;
    #pragma unroll
    for (int mt = 0; mt < 4; mt++)
      #pragma unroll
      for (int reg = 0; reg < 4; reg++) {
        int p = mt * 16 + lg * 4 + reg;
        if (p < WS2) {
          #pragma unroll
          for (int nt2 = 0; nt2 < 2; nt2++)
            ob[(size_t)p * (NWIN * HDD) + nt2 * 16 + lm] = o[mt][nt2][reg];
        }
      }
  }
}

// ---------- K3: conv (49-tap over p') + projection ----------
__global__ void k3_conv_proj(const float* __restrict__ o_ws,
                             const float* __restrict__ conv_w,
                             const float* __restrict__ conv_b,
                             const float* __restrict__ w_proj,
                             const float* __restrict__ b_proj,
                             float* __restrict__ out) {
  __shared__ float yv[CC];
  __shared__ float cw[WS2];
  const int tid = threadIdx.x;
  const int np = blockIdx.x;
  const int b = blockIdx.y;
  if (tid < WS2) cw[tid] = conv_w[tid];
  __syncthreads();
  const float* base = o_ws + (size_t)b * O_PER_B + (size_t)np * (WS2 * CC);
  float acc = conv_b[0];
  for (int p = 0; p < WS2; p++)
    acc += cw[p] * base[p * CC + tid];
  yv[tid] = acc;
  __syncthreads();
  const float4* y4 = (const float4*)yv;
  const float4* w4 = (const float4*)(w_proj + (size_t)tid * CC);
  float s = b_proj[tid];
  float s2 = 0.0f;
  #pragma unroll 8
  for (int c4 = 0; c4 < 64; c4++) {
    float4 a = y4[c4], wv2 = w4[c4];
    s2 += a.x * wv2.x + a.y * wv2.y + a.z * wv2.z + a.w * wv2.w;
  }
  out[((size_t)(b * NWIN + np)) * CC + tid] = s + s2;
}

extern "C" void kernel_launch(void* const* d_in, const int* in_sizes, int n_in,
                              void* d_out, int out_size, void* d_ws, size_t ws_size,
                              hipStream_t stream) {
  const float* x        = (const float*)d_in[0];
  const float* polys    = (const float*)d_in[1];
  const float* w_qkv    = (const float*)d_in[2];
  const float* b_qkv    = (const float*)d_in[3];
  const float* w_proj   = (const float*)d_in[4];
  const float* b_proj   = (const float*)d_in[5];
  const float* conv_w   = (const float*)d_in[6];
  const float* conv_b   = (const float*)d_in[7];
  float* out = (float*)d_out;

  char* ws = (char*)d_ws;
  float* xT = (float*)ws;
  unsigned short* wbp = (unsigned short*)(ws + XT_BYTES);
  unsigned short* qkv_ws = (unsigned short*)(ws + XT_BYTES + WB_BYTES);
  float* o_ws = (float*)(ws + XT_BYTES + WB_BYTES + QKV_BYTES);

  hipLaunchKernelGGL(k0_transpose, dim3(128, 8, 2), dim3(32, 8), 0, stream, x, xT);
  hipLaunchKernelGGL(k05_wpack, dim3(96), dim3(256), 0, stream, w_qkv, wbp);
  hipLaunchKernelGGL(k1_sample_qkv, dim3(NWIN, B_), dim3(256), 0, stream,
                     xT, polys, wbp, b_qkv, qkv_ws);
  hipLaunchKernelGGL(k2_attn, dim3(NWIN, B_), dim3(256), 0, stream,
                     qkv_ws, o_ws);
  hipLaunchKernelGGL(k3_conv_proj, dim3(NWIN, B_), dim3(256), 0, stream,
                     o_ws, conv_w, conv_b, w_proj, b_proj, out);
}